// Round 1
// baseline (268.506 us; speedup 1.0000x reference)
//
#include <hip/hip_runtime.h>

// Problem: 3x3 VALID conv, NCHW fp32.
// data: [16, 64, 128, 128], weights: [128, 64, 3, 3] -> out [16, 128, 126, 126]
// Strategy: NHWC-bf16 pre-transpose + implicit-GEMM MFMA (16x16x32 bf16),
// m97-style 128co x 128spatial block tile, K = 64ci x 9 taps.

#define BATCH 16
#define CIN   64
#define HIN   128
#define WIN   128
#define COUT  128
#define HO    126
#define WO    126

typedef short bf16x8 __attribute__((ext_vector_type(8)));
typedef float f32x4  __attribute__((ext_vector_type(4)));

__device__ __forceinline__ unsigned short f2bf(float f) {
    union { float f; unsigned int u; } v; v.f = f;
    unsigned int u = v.u;
    unsigned int r = (u + 0x7fffu + ((u >> 16) & 1u)) >> 16;
    return (unsigned short)r;
}

// async global->LDS, 16B per lane. LDS dest = wave-uniform base + lane*16.
__device__ __forceinline__ void async16(const void* g, void* l) {
    __builtin_amdgcn_global_load_lds(
        (const __attribute__((address_space(1))) unsigned int*)(unsigned long long)g,
        (__attribute__((address_space(3))) unsigned int*)(unsigned long long)l,
        16, 0, 0);
}

// ---------- Pre-pass 1: NCHW fp32 -> NHWC bf16 ----------
// grid (2, 128, 16), block 256. Tile: [ci 0..63] x [w0..w0+63] for fixed (b,h).
__global__ __launch_bounds__(256) void t1_nchw_to_nhwc(
        const float* __restrict__ x, unsigned short* __restrict__ y) {
    __shared__ unsigned short tile[64 * 68]; // [w][ci], pad 68 keeps 8B align
    const int b = blockIdx.z, h = blockIdx.y, w0 = blockIdx.x * 64;
    const int t = threadIdx.x;

    const int wl = t & 63, ci0 = t >> 6; // ci0 in 0..3
    const float* src = x + (((size_t)b * CIN) * HIN + h) * WIN + w0 + wl;
#pragma unroll
    for (int j = 0; j < 16; j++) {
        const int ci = ci0 + j * 4;
        tile[wl * 68 + ci] = f2bf(src[(size_t)ci * (HIN * WIN)]);
    }
    __syncthreads();

    const int ci4 = (t & 15) * 4, wl2 = t >> 4; // wl2 in 0..15
#pragma unroll
    for (int j = 0; j < 4; j++) {
        const int w = wl2 + j * 16;
        ushort4 v = *(const ushort4*)&tile[w * 68 + ci4];
        *(ushort4*)&y[(((size_t)b * HIN + h) * WIN + w0 + w) * CIN + ci4] = v;
    }
}

// ---------- Pre-pass 2: weights [co][ci][kh][kw] fp32 -> [kh*3+kw][co][ci] bf16 ----------
__global__ __launch_bounds__(256) void t2_weights(
        const float* __restrict__ w, unsigned short* __restrict__ wt) {
    const int idx = blockIdx.x * 256 + threadIdx.x;
    if (idx < COUT * CIN * 9) {
        const int co = idx / (CIN * 9);
        const int r  = idx % (CIN * 9);
        const int ci = r / 9;
        const int k  = r % 9;
        wt[((size_t)k * COUT + co) * CIN + ci] = f2bf(w[idx]);
    }
}

// ---------- Main: implicit-GEMM MFMA conv ----------
// grid (8 wtiles, 16 htiles, 16 b), block 256 (4 waves in 2x2).
// Block tile: 128 co x (8h x 16w) spatial. K-loop: 9 taps x 64 ci.
__global__ __launch_bounds__(256) void conv_mfma(
        const unsigned short* __restrict__ nhwc,   // [b][h][w][ci] bf16
        const unsigned short* __restrict__ wt,     // [tap][co][ci] bf16
        float* __restrict__ out) {
    __shared__ short As[128 * 64]; // [co][ci] 16 KB
    __shared__ short Bs[128 * 64]; // [n=dy*16+dx][ci] 16 KB

    const int w0 = blockIdx.x * 16;
    const int h0 = blockIdx.y * 8;
    const int b  = blockIdx.z;
    const int tid = threadIdx.x;
    const int lane = tid & 63, wave = tid >> 6;
    const int wm = wave & 1, wn = wave >> 1;
    const int col = lane & 15, quad = lane >> 4;

    f32x4 acc[4][4] = {};

    for (int t = 0; t < 9; t++) {
        const int kh = t / 3, kw = t % 3;
        if (t) __syncthreads();

        // Stage As: contiguous 16 KB slice of transformed weights.
        {
            const char* src = (const char*)wt + (size_t)t * 16384;
            char* dst = (char*)As;
#pragma unroll
            for (int i = 0; i < 4; i++) {
                const int c = wave * 4 + i;
                async16(src + c * 1024 + lane * 16, dst + c * 1024 + lane * 16);
            }
        }
        // Stage Bs: per dy row, 2048 contiguous bytes (16 w x 64 ci bf16).
        {
#pragma unroll
            for (int i = 0; i < 2; i++) {
                const int dy = wave * 2 + i;
                int h = h0 + dy + kh;
                if (h > HIN - 1) h = HIN - 1; // clamp: feeds only masked outputs
                const char* src = (const char*)nhwc +
                    ((size_t)((b * HIN + h) * WIN + w0 + kw)) * (CIN * 2);
                char* dst = (char*)Bs + dy * 2048;
                async16(src + lane * 16, dst + lane * 16);
                async16(src + 1024 + lane * 16, dst + 1024 + lane * 16);
            }
        }
        __syncthreads(); // compiler emits vmcnt(0) drain before barrier

#pragma unroll
        for (int kk = 0; kk < 2; kk++) {
            const int k0 = kk * 32;
            bf16x8 a[4], bb[4];
#pragma unroll
            for (int mi = 0; mi < 4; mi++)
                a[mi] = *(const bf16x8*)&As[(wm * 64 + mi * 16 + col) * 64 + k0 + quad * 8];
#pragma unroll
            for (int ni = 0; ni < 4; ni++)
                bb[ni] = *(const bf16x8*)&Bs[(wn * 64 + ni * 16 + col) * 64 + k0 + quad * 8];
#pragma unroll
            for (int mi = 0; mi < 4; mi++)
#pragma unroll
                for (int ni = 0; ni < 4; ni++)
                    acc[mi][ni] = __builtin_amdgcn_mfma_f32_16x16x32_bf16(
                        a[mi], bb[ni], acc[mi][ni], 0, 0, 0);
        }
    }

    // Epilogue. C/D layout: col(N=spatial)=lane&15, row(M=co)=quad*4+reg.
    const int ow = w0 + col;
#pragma unroll
    for (int ni = 0; ni < 4; ni++) {
        const int oh = h0 + wn * 4 + ni;
        if (oh < HO && ow < WO) {
#pragma unroll
            for (int mi = 0; mi < 4; mi++) {
                const int co = wm * 64 + mi * 16 + quad * 4;
                float* o = out + (((size_t)b * COUT + co) * HO + oh) * WO + ow;
#pragma unroll
                for (int r = 0; r < 4; r++)
                    o[(size_t)r * HO * WO] = acc[mi][ni][r];
            }
        }
    }
}

// ---------- Fallback: direct fp32 conv (if d_ws too small) ----------
__global__ __launch_bounds__(256) void conv_direct(
        const float* __restrict__ x, const float* __restrict__ w,
        float* __restrict__ y) {
    const int idx = blockIdx.x * 256 + threadIdx.x;
    if (idx >= BATCH * COUT * HO * WO) return;
    const int ow = idx % WO;
    int t = idx / WO;
    const int oh = t % HO; t /= HO;
    const int co = t % COUT;
    const int b  = t / COUT;
    float acc = 0.f;
    const float* xb = x + (((size_t)b * CIN) * HIN + oh) * WIN + ow;
    const float* wc = w + (size_t)co * (CIN * 9);
    for (int ci = 0; ci < CIN; ci++) {
#pragma unroll
        for (int kh = 0; kh < 3; kh++)
#pragma unroll
            for (int kw = 0; kw < 3; kw++)
                acc += xb[(size_t)ci * (HIN * WIN) + kh * WIN + kw] * wc[ci * 9 + kh * 3 + kw];
    }
    y[idx] = acc;
}

extern "C" void kernel_launch(void* const* d_in, const int* in_sizes, int n_in,
                              void* d_out, int out_size, void* d_ws, size_t ws_size,
                              hipStream_t stream) {
    const float* data    = (const float*)d_in[0];
    const float* weights = (const float*)d_in[1];
    float* out = (float*)d_out;

    const size_t nhwc_bytes = (size_t)BATCH * HIN * WIN * CIN * 2; // 32 MiB
    const size_t slack = 4096;                                      // halo overflow pad
    const size_t wt_bytes = (size_t)9 * COUT * CIN * 2;             // 144 KiB
    const size_t need = nhwc_bytes + slack + wt_bytes;

    if (ws_size >= need) {
        unsigned short* nhwc = (unsigned short*)d_ws;
        unsigned short* wt   = (unsigned short*)((char*)d_ws + nhwc_bytes + slack);
        t1_nchw_to_nhwc<<<dim3(2, HIN, BATCH), 256, 0, stream>>>(data, nhwc);
        t2_weights<<<(COUT * CIN * 9 + 255) / 256, 256, 0, stream>>>(weights, wt);
        conv_mfma<<<dim3(8, 16, BATCH), 256, 0, stream>>>(nhwc, wt, out);
    } else {
        const int n = BATCH * COUT * HO * WO;
        conv_direct<<<(n + 255) / 256, 256, 0, stream>>>(data, weights, out);
    }
}